// Round 1
// baseline (1405.918 us; speedup 1.0000x reference)
//
#include <hip/hip_runtime.h>
#include <hip/hip_bf16.h>

#define B_ 128
#define C_ 1024
#define H_ 16
#define LD1 3392   // G1OUT row width: r(1024) k(1024) vwv(1024) lora1(288) scales(32)

typedef float f32x4 __attribute__((ext_vector_type(4)));
typedef short bf16x8 __attribute__((ext_vector_type(8)));

__device__ inline unsigned short f2bf(float x){
  unsigned u = __float_as_uint(x);
  return (unsigned short)((u + 0x7fffu + ((u>>16)&1u)) >> 16);
}
__device__ inline unsigned long long pack4(float a,float b,float c,float d){
  unsigned lo = (unsigned)f2bf(a) | ((unsigned)f2bf(b)<<16);
  unsigned hi = (unsigned)f2bf(c) | ((unsigned)f2bf(d)<<16);
  return (unsigned long long)lo | ((unsigned long long)hi<<32);
}
__device__ inline float sigm(float x){ return 1.f/(1.f+expf(-x)); }
__device__ inline float wsum(float v){
  #pragma unroll
  for(int o=32;o;o>>=1) v += __shfl_xor(v,o);
  return v;
}
// LDS swizzle (u16 index units, row stride 64 or 128 u16): XOR row bits into 16B-slot bits
__device__ inline int swz64(int r,int c){ return (r*64+c) ^ ((r&7)<<3); }
__device__ inline int swz128(int r,int c){ return (r*128+c) ^ ((r&7)<<3); }

// ---------------- time-mix prep: LN + 8-way lerp -> bf16 mixed[8][B][C] ----------------
__launch_bounds__(256)
__global__ void tmix_prep(const float* __restrict__ x, const float* __restrict__ lnw,
                          const float* __restrict__ lnb, const float* __restrict__ lerp8,
                          const float* __restrict__ xs, unsigned short* __restrict__ mixed){
  int b = blockIdx.x, tid = threadIdx.x;
  const float* xr = x + b*C_;
  f32x4 v = ((const f32x4*)xr)[tid];
  float s  = v[0]+v[1]+v[2]+v[3];
  float ss = v[0]*v[0]+v[1]*v[1]+v[2]*v[2]+v[3]*v[3];
  __shared__ float red[8];
  s = wsum(s); ss = wsum(ss);
  int lane = tid&63, wv = tid>>6;
  if (lane==0){ red[wv]=s; red[4+wv]=ss; }
  __syncthreads();
  float S1 = red[0]+red[1]+red[2]+red[3];
  float S2 = red[4]+red[5]+red[6]+red[7];
  float m = S1*(1.f/C_);
  float var = S2*(1.f/C_) - m*m;
  float inv = rsqrtf(var + 1e-5f);
  int c0 = tid*4;
  float xl[4], xsv[4];
  #pragma unroll
  for(int j=0;j<4;++j){
    xl[j]  = (v[j]-m)*inv*lnw[c0+j] + lnb[c0+j];
    xsv[j] = xs[b*C_ + c0 + j];
  }
  #pragma unroll
  for(int jj=0;jj<8;++jj){
    float o[4];
    #pragma unroll
    for(int j=0;j<4;++j){
      float t = lerp8[jj*C_ + c0 + j];
      o[j] = xl[j] + t*(xsv[j]-xl[j]);
    }
    *(unsigned long long*)&mixed[jj*(B_*C_) + b*C_ + c0] = pack4(o[0],o[1],o[2],o[3]);
  }
}

// ---------------- channel-mix prep: LN + lerp_k -> bf16 mixc[B][C] ----------------
__launch_bounds__(256)
__global__ void cmix_prep(const float* __restrict__ x, const float* __restrict__ lnw,
                          const float* __restrict__ lnb, const float* __restrict__ lk,
                          const float* __restrict__ xs, unsigned short* __restrict__ out){
  int b = blockIdx.x, tid = threadIdx.x;
  const float* xr = x + b*C_;
  f32x4 v = ((const f32x4*)xr)[tid];
  float s  = v[0]+v[1]+v[2]+v[3];
  float ss = v[0]*v[0]+v[1]*v[1]+v[2]*v[2]+v[3]*v[3];
  __shared__ float red[8];
  s = wsum(s); ss = wsum(ss);
  int lane = tid&63, wv = tid>>6;
  if (lane==0){ red[wv]=s; red[4+wv]=ss; }
  __syncthreads();
  float S1 = red[0]+red[1]+red[2]+red[3];
  float S2 = red[4]+red[5]+red[6]+red[7];
  float m = S1*(1.f/C_);
  float var = S2*(1.f/C_) - m*m;
  float inv = rsqrtf(var + 1e-5f);
  int c0 = tid*4;
  float o[4];
  #pragma unroll
  for(int j=0;j<4;++j){
    float xl = (v[j]-m)*inv*lnw[c0+j] + lnb[c0+j];
    float t = lk[c0+j];
    o[j] = xl + t*(xs[b*C_+c0+j]-xl);
  }
  *(unsigned long long*)&out[b*C_ + c0] = pack4(o[0],o[1],o[2],o[3]);
}

// ---------------- generic MFMA GEMM core: M=128, Ntile=32, BK=64, bf16 A (global), f32 W ----------------
// out accumulated with f32 atomics (split-K). LDS tiles swizzled; W transposed to [n][k] in LDS.
__device__ __forceinline__ void gemm_core(unsigned short* lA, unsigned short* lB,
    const unsigned short* __restrict__ A, int lda,
    const float* __restrict__ W, int ldw, int wcol, int wtrans, int nvalid,
    float* __restrict__ out, int ldo, int ocol, int kt0, int kIters)
{
  int tid = threadIdx.x;
  int lane = tid&63, w = tid>>6, lo = lane&15, hi = lane>>4;
  f32x4 acc[2][2] = {};
  for (int kb=0; kb<kIters; ++kb){
    int k0 = kt0 + kb*64;
    #pragma unroll
    for (int p=0;p<8;++p){           // stage A: 128x64 bf16
      int idx = tid + p*256; int m = idx>>4; int c4 = (idx&15)<<2;
      *(unsigned long long*)&lA[swz64(m,c4)] = *(const unsigned long long*)(A + m*lda + k0 + c4);
    }
    int n = tid&31, kp = tid>>5;
    #pragma unroll
    for (int p=0;p<4;++p){           // stage W: 64x32 f32 -> [n][k] bf16
      int kl = p*16 + kp*2;
      float w0=0.f, w1=0.f;
      if (!wtrans){
        const float* wp = W + (k0+kl)*ldw + wcol + n;
        w0 = wp[0]; w1 = wp[ldw];
      } else if (n < nvalid){
        const float* wp = W + (wcol+n)*1024 + k0 + kl;
        w0 = wp[0]; w1 = wp[1];
      }
      unsigned pk = (unsigned)f2bf(w0) | ((unsigned)f2bf(w1)<<16);
      *(unsigned*)&lB[swz64(n,kl)] = pk;
    }
    __syncthreads();
    #pragma unroll
    for (int ks=0;ks<2;++ks){
      int kk = ks*32 + hi*8;
      bf16x8 a0 = *(const bf16x8*)&lA[swz64(w*32+lo, kk)];
      bf16x8 a1 = *(const bf16x8*)&lA[swz64(w*32+16+lo, kk)];
      bf16x8 b0 = *(const bf16x8*)&lB[swz64(lo, kk)];
      bf16x8 b1 = *(const bf16x8*)&lB[swz64(16+lo, kk)];
      acc[0][0] = __builtin_amdgcn_mfma_f32_16x16x32_bf16(a0,b0,acc[0][0],0,0,0);
      acc[0][1] = __builtin_amdgcn_mfma_f32_16x16x32_bf16(a0,b1,acc[0][1],0,0,0);
      acc[1][0] = __builtin_amdgcn_mfma_f32_16x16x32_bf16(a1,b0,acc[1][0],0,0,0);
      acc[1][1] = __builtin_amdgcn_mfma_f32_16x16x32_bf16(a1,b1,acc[1][1],0,0,0);
    }
    __syncthreads();
  }
  #pragma unroll
  for (int mf=0;mf<2;++mf)
  #pragma unroll
  for (int nf=0;nf<2;++nf){
    int cl = nf*16 + lo;
    if (cl < nvalid){
      #pragma unroll
      for (int i=0;i<4;++i){
        int row = w*32 + mf*16 + hi*4 + i;
        unsafeAtomicAdd(&out[row*ldo + ocol + cl], acc[mf][nf][i]);
      }
    }
  }
}

// ---------------- GEMM1: r/k/v + LoRA-A stage1 + ks/vs (107 tiles x 4 K-splits) ----------------
struct G1Args { const unsigned short* mixed; const float* W[9]; float* out; };

__launch_bounds__(256)
__global__ void gemm1_k(G1Args a){
  __shared__ unsigned short lA[128*64];
  __shared__ unsigned short lB[32*64];
  int t = blockIdx.x;
  int wsel, asel, wcol=0, ldw=1024, ocol, wtrans=0, nvalid=32;
  if (t < 96)      { int g=t>>5, s=t&31; wsel=g; asel=g; wcol=s*32; ocol=g*1024+s*32; }
  else if (t==96)  { wsel=3; asel=2; ldw=32;  ocol=3072; }
  else if (t<=98)  { int s=t-97;  wsel=4; asel=4; ldw=64;  wcol=s*32; ocol=3104+s*32; }
  else if (t<=100) { int s=t-99;  wsel=5; asel=3; ldw=64;  wcol=s*32; ocol=3168+s*32; }
  else if (t<=104) { int s=t-101; wsel=6; asel=5; ldw=128; wcol=s*32; ocol=3232+s*32; }
  else if (t==105) { wsel=7; asel=6; wtrans=1; nvalid=16; ocol=3360; }
  else             { wsel=8; asel=7; wtrans=1; nvalid=16; ocol=3376; }
  gemm_core(lA,lB, a.mixed + asel*(B_*C_), C_, a.W[wsel], ldw, wcol, wtrans, nvalid,
            a.out, LD1, ocol, blockIdx.y*256, 4);
}

// ---------------- uniform GEMM (Wo / cW_k / cW_v): atomic accumulate ----------------
__launch_bounds__(256)
__global__ void gemm_sk(const unsigned short* __restrict__ A, int lda,
                        const float* __restrict__ W, int ldw,
                        float* __restrict__ out, int ldo, int kIters){
  __shared__ unsigned short lA[128*64];
  __shared__ unsigned short lB[32*64];
  int wcol = blockIdx.x*32;
  gemm_core(lA,lB, A, lda, W, ldw, wcol, 0, 32, out, ldo, wcol, blockIdx.y*kIters*64, kIters);
}

// ---------------- GEMM2: LoRA-B stage with fused pre-nonlinearity + epilogues (BK=128 padded) ----------------
struct G2Args {
  const float* g1; const float* vB; const float* aB; const float* dB; const float* gB;
  const float* vbias; const float* abias; const float* dbias;
  float* vfin; float* afin; float* wfin; float* gfin; float* v0;
  int first;
};

__launch_bounds__(256)
__global__ void gemm2_k(G2Args a){
  __shared__ unsigned short lA[128*128];
  __shared__ unsigned short lB[32*128];
  int t = blockIdx.x;
  int grp = t>>5, s = t&31;
  int Kd, acol, aop; const float* W;
  if (grp==0){ Kd=32;  acol=3072; aop=0; W=a.vB; }
  else if (grp==1){ Kd=64; acol=3104; aop=0; W=a.aB; }
  else if (grp==2){ Kd=64; acol=3168; aop=1; W=a.dB; }
  else { Kd=128; acol=3232; aop=2; W=a.gB; }
  int wcol = s*32;
  int tid = threadIdx.x, lane = tid&63, w = tid>>6, lo = lane&15, hi = lane>>4;
  #pragma unroll
  for (int p=0;p<16;++p){            // stage A (f32 -> nonlin -> bf16), zero-pad to K=128
    int idx = tid + p*256; int m = idx>>5; int c4 = (idx&31)<<2;
    unsigned long long val = 0ull;
    if (c4 < Kd){
      f32x4 v = *(const f32x4*)&a.g1[m*LD1 + acol + c4];
      float e0=v[0],e1=v[1],e2=v[2],e3=v[3];
      if (aop==1){ e0=tanhf(e0); e1=tanhf(e1); e2=tanhf(e2); e3=tanhf(e3); }
      else if (aop==2){ e0=sigm(e0); e1=sigm(e1); e2=sigm(e2); e3=sigm(e3); }
      val = pack4(e0,e1,e2,e3);
    }
    *(unsigned long long*)&lA[swz128(m,c4)] = val;
  }
  int n = tid&31, kp = tid>>5;
  #pragma unroll
  for (int p=0;p<8;++p){             // stage W [n][k], zero-pad
    int kl = p*16 + kp*2;
    float w0=0.f, w1=0.f;
    if (kl < Kd){ const float* wp = W + kl*1024 + wcol + n; w0 = wp[0]; w1 = wp[1024]; }
    unsigned pk = (unsigned)f2bf(w0) | ((unsigned)f2bf(w1)<<16);
    *(unsigned*)&lB[swz128(n,kl)] = pk;
  }
  __syncthreads();
  f32x4 acc[2][2] = {};
  #pragma unroll
  for (int ks=0;ks<4;++ks){
    int kk = ks*32 + hi*8;
    bf16x8 a0 = *(const bf16x8*)&lA[swz128(w*32+lo, kk)];
    bf16x8 a1 = *(const bf16x8*)&lA[swz128(w*32+16+lo, kk)];
    bf16x8 b0 = *(const bf16x8*)&lB[swz128(lo, kk)];
    bf16x8 b1 = *(const bf16x8*)&lB[swz128(16+lo, kk)];
    acc[0][0] = __builtin_amdgcn_mfma_f32_16x16x32_bf16(a0,b0,acc[0][0],0,0,0);
    acc[0][1] = __builtin_amdgcn_mfma_f32_16x16x32_bf16(a0,b1,acc[0][1],0,0,0);
    acc[1][0] = __builtin_amdgcn_mfma_f32_16x16x32_bf16(a1,b0,acc[1][0],0,0,0);
    acc[1][1] = __builtin_amdgcn_mfma_f32_16x16x32_bf16(a1,b1,acc[1][1],0,0,0);
  }
  #pragma unroll
  for (int mf=0;mf<2;++mf)
  #pragma unroll
  for (int nf=0;nf<2;++nf)
  #pragma unroll
  for (int i=0;i<4;++i){
    int row = w*32 + mf*16 + hi*4 + i;
    int c = wcol + nf*16 + lo;
    float x = acc[mf][nf][i];
    int o = row*C_ + c;
    if (grp==3){ a.gfin[o] = x; }
    else if (grp==1){ a.afin[o] = sigm(x + a.abias[c]); }
    else if (grp==2){
      float d = x + a.dbias[c];
      float sp = log1pf(expf(-d));            // softplus(-d)
      a.wfin[o] = expf(-expf(-0.5f - sp));
    } else {
      float vwv = a.g1[row*LD1 + 2048 + c];
      if (a.first){ a.vfin[o] = vwv; a.v0[o] = vwv; }
      else { float vm = sigm(x + a.vbias[c]); a.vfin[o] = vwv + vm*(a.v0[o] - vwv); }
    }
  }
}

// ---------------- state kernel: one wave per (b,h); rank-1 delta rule, GN, bonus ----------------
__launch_bounds__(256)
__global__ void state_k(const float* __restrict__ g1, const float* __restrict__ vfin,
                        const float* __restrict__ afin, const float* __restrict__ wfin,
                        const float* __restrict__ gfin, const float* __restrict__ S,
                        const float* __restrict__ bon, const float* __restrict__ ksb,
                        const float* __restrict__ vsb, const float* __restrict__ gnw,
                        const float* __restrict__ gnb, unsigned short* __restrict__ y){
  __shared__ __align__(16) float lt[4][2][64];
  int wv = threadIdx.x>>6, lane = threadIdx.x&63;
  int pair = blockIdx.x*4 + wv;
  int b = pair>>4, h = pair&15;
  const float* g1r = g1 + b*LD1;
  int ci = h*64 + lane;
  float r  = g1r[ci];
  float k  = g1r[1024+ci];
  float v  = vfin[b*C_+ci];
  float aa = afin[b*C_+ci];
  float ww = wfin[b*C_+ci];
  float gg = gfin[b*C_+ci];
  float ks = sigm(g1r[3360+h] + ksb[h]);
  float vs = sigm(g1r[3376+h] + vsb[h]);
  float nk = sqrtf(wsum(k*k));
  float kkv = ks * k / fmaxf(nk, 1e-12f);
  float nv = sqrtf(wsum(v*v));
  float vh = vs * v / fmaxf(nv, 1e-12f);
  float kh = kkv * aa;
  float khrh = wsum(kh*r);
  float bkr  = wsum(r * bon[h*64+lane] * kh);
  lt[wv][0][lane] = ww*r;
  lt[wv][1][lane] = kkv;
  __syncthreads();
  const float* Sr = S + ((size_t)((b*16+h)*64 + lane))*64;
  float s1=0.f, s2=0.f;
  #pragma unroll
  for (int j=0;j<16;++j){
    f32x4 sv = *(const f32x4*)&Sr[j*4];
    f32x4 u1 = *(const f32x4*)&lt[wv][0][j*4];
    f32x4 u2 = *(const f32x4*)&lt[wv][1][j*4];
    s1 += sv[0]*u1[0]+sv[1]*u1[1]+sv[2]*u1[2]+sv[3]*u1[3];
    s2 += sv[0]*u2[0]+sv[1]*u2[1]+sv[2]*u2[2]+sv[3]*u2[3];
  }
  float out = s1 + (vh - s2)*khrh;            // (Sn @ rh)[lane]
  float mu = wsum(out)*(1.f/64.f);
  float dev = out - mu;
  float var = wsum(dev*dev)*(1.f/64.f);
  float gn = dev*rsqrtf(var + 6.4e-4f)*gnw[ci] + gnb[ci];
  float yv = gg*(gn + bkr*vh);
  y[b*C_+ci] = f2bf(yv);
}

// ---------------- relu^2 -> bf16 ----------------
__launch_bounds__(256)
__global__ void relu2_k(const float* __restrict__ h, unsigned short* __restrict__ o){
  int i = (blockIdx.x*256 + threadIdx.x)*4;
  f32x4 v = *(const f32x4*)&h[i];
  float r0 = fmaxf(v[0],0.f); r0*=r0;
  float r1 = fmaxf(v[1],0.f); r1*=r1;
  float r2 = fmaxf(v[2],0.f); r2*=r2;
  float r3 = fmaxf(v[3],0.f); r3*=r3;
  *(unsigned long long*)&o[i] = pack4(r0,r1,r2,r3);
}

extern "C" void kernel_launch(void* const* d_in, const int* in_sizes, int n_in,
                              void* d_out, int out_size, void* d_ws, size_t ws_size,
                              hipStream_t stream){
  const float* in_BC  = (const float*)d_in[0];
  const float* txs    = (const float*)d_in[1];
  const float* tstate = (const float*)d_in[2];
  const float* cxs    = (const float*)d_in[3];
  const float* lntw   = (const float*)d_in[4];
  const float* lntb   = (const float*)d_in[5];
  const float* lerp8  = (const float*)d_in[6];
  const float* bon    = (const float*)d_in[7];
  const float* Wr     = (const float*)d_in[8];
  const float* Wk     = (const float*)d_in[9];
  const float* Wv     = (const float*)d_in[10];
  const float* Wo     = (const float*)d_in[11];
  const float* ksW    = (const float*)d_in[12];
  const float* ksb    = (const float*)d_in[13];
  const float* vsW    = (const float*)d_in[14];
  const float* vsb    = (const float*)d_in[15];
  const float* vA     = (const float*)d_in[16];
  const float* vBp    = (const float*)d_in[17];
  const float* vbias  = (const float*)d_in[18];
  const float* aA     = (const float*)d_in[19];
  const float* aB     = (const float*)d_in[20];
  const float* abias  = (const float*)d_in[21];
  const float* dA     = (const float*)d_in[22];
  const float* dB     = (const float*)d_in[23];
  const float* dbias  = (const float*)d_in[24];
  const float* gA     = (const float*)d_in[25];
  const float* gB     = (const float*)d_in[26];
  const float* gnw    = (const float*)d_in[27];
  const float* gnb    = (const float*)d_in[28];
  const float* lncw   = (const float*)d_in[29];
  const float* lncb   = (const float*)d_in[30];
  const float* lkc    = (const float*)d_in[31];
  const float* cWk    = (const float*)d_in[32];
  const float* cWv    = (const float*)d_in[33];

  char* ws = (char*)d_ws;
  float* xA           = (float*)(ws + 0);         // 512KB
  float* xB           = (float*)(ws + 524288);    // 512KB
  unsigned short* mixed = (unsigned short*)(ws + 1048576);  // 2MB bf16 (8,B,C)
  float* g1o          = (float*)(ws + 3145728);   // (B,3392) f32
  float* vfin         = (float*)(ws + 4882432);
  float* afin         = (float*)(ws + 5406720);
  float* wfin         = (float*)(ws + 5931008);
  float* gfin         = (float*)(ws + 6455296);
  float* v0           = (float*)(ws + 6979584);
  unsigned short* ybuf = (unsigned short*)(ws + 7503872);   // 256KB bf16
  unsigned short* mixc = (unsigned short*)(ws + 7766016);   // 256KB bf16
  float* hbuf         = (float*)(ws + 8028160);   // 2MB (B,4096)
  unsigned short* h2  = (unsigned short*)(ws + 10125312);   // 1MB bf16

  hipMemcpyAsync(xA, in_BC, 524288, hipMemcpyDeviceToDevice, stream);
  float* x = xA; float* xt = xB;
  for (int l=0; l<12; ++l){
    tmix_prep<<<128,256,0,stream>>>(x, lntw+l*1024, lntb+l*1024, lerp8+l*8192, txs+l*131072, mixed);
    hipMemsetAsync(g1o, 0, 128*3392*4, stream);
    G1Args a1;
    a1.mixed = mixed;
    a1.W[0] = Wr + (size_t)l*1048576; a1.W[1] = Wk + (size_t)l*1048576; a1.W[2] = Wv + (size_t)l*1048576;
    a1.W[3] = vA + l*32768; a1.W[4] = aA + l*65536; a1.W[5] = dA + l*65536; a1.W[6] = gA + l*131072;
    a1.W[7] = ksW + l*16384; a1.W[8] = vsW + l*16384;
    a1.out = g1o;
    gemm1_k<<<dim3(107,4),256,0,stream>>>(a1);
    G2Args a2;
    a2.g1 = g1o; a2.vB = vBp + l*32768; a2.aB = aB + l*65536; a2.dB = dB + l*65536; a2.gB = gB + l*131072;
    a2.vbias = vbias + l*1024; a2.abias = abias + l*1024; a2.dbias = dbias + l*1024;
    a2.vfin = vfin; a2.afin = afin; a2.wfin = wfin; a2.gfin = gfin; a2.v0 = v0; a2.first = (l==0);
    gemm2_k<<<128,256,0,stream>>>(a2);
    state_k<<<512,256,0,stream>>>(g1o, vfin, afin, wfin, gfin,
                                  tstate + (size_t)l*8388608, bon + l*1024,
                                  ksb + l*16, vsb + l*16, gnw + l*1024, gnb + l*1024, ybuf);
    hipMemcpyAsync(xt, x, 524288, hipMemcpyDeviceToDevice, stream);
    gemm_sk<<<dim3(32,4),256,0,stream>>>(ybuf, 1024, Wo + (size_t)l*1048576, 1024, xt, 1024, 4);
    cmix_prep<<<128,256,0,stream>>>(xt, lncw+l*1024, lncb+l*1024, lkc+l*1024, cxs+l*131072, mixc);
    hipMemsetAsync(hbuf, 0, 128*4096*4, stream);
    gemm_sk<<<dim3(128,2),256,0,stream>>>(mixc, 1024, cWk + (size_t)l*4194304, 4096, hbuf, 4096, 8);
    relu2_k<<<512,256,0,stream>>>(hbuf, h2);
    gemm_sk<<<dim3(32,8),256,0,stream>>>(h2, 4096, cWv + (size_t)l*4194304, 1024, xt, 1024, 8);
    float* tmp = x; x = xt; xt = tmp;
  }
  hipMemcpyAsync(d_out, x, 524288, hipMemcpyDeviceToDevice, stream);
}